// Round 19
// baseline (64.805 us; speedup 1.0000x reference)
//
#include <hip/hip_runtime.h>
#include <math.h>
#include <stdint.h>

// Problem dims
#define NB  8
#define NC  256
#define NHW 4096   // H*W
#define NK  512

// d_out float offsets (outputs concatenated in return order)
#define OFF_SEL 0ULL
#define OFF_CW  8388608ULL              // NB*NC*NHW
#define OFF_KLD 8421376ULL              // + NB*NHW
#define OFF_MAT 8421377ULL              // + 1
#define MAT_COUNT 16777216ULL           // NB*NK*NHW
#define OUT_TOTAL (OFF_MAT + MAT_COUNT) // 25198593

// ws layout: double sw[512]; double kld_accum;  (4104 bytes)

// DPP helpers: xor1=0xB1, xor2=0x4E, xor7(row_half_mirror)=0x141, xor15(row_mirror)=0x140
template <int C>
__device__ __forceinline__ float fdpp(float x) {
    return __int_as_float(__builtin_amdgcn_update_dpp(0, __float_as_int(x), C, 0xF, 0xF, true));
}
template <int C>
__device__ __forceinline__ int idpp(int x) {
    return __builtin_amdgcn_update_dpp(0, x, C, 0xF, 0xF, true);
}
__device__ __forceinline__ float fswz16(float x) {   // lane ^ 16
    return __int_as_float(__builtin_amdgcn_ds_swizzle(__float_as_int(x), 0x401F));
}
__device__ __forceinline__ int iswz16(int x) {
    return __builtin_amdgcn_ds_swizzle(x, 0x401F);
}

// Small prep: codebook channel-sum -> ws[0..511] (f64) + kld accumulator zero.
__global__ void prep(const float* __restrict__ cb, double* __restrict__ ws) {
    const int l = threadIdx.x & 63;
    const int w = threadIdx.x >> 6;
    const int k = blockIdx.x * 4 + w;           // grid 128 x 256 threads -> k in [0,512)
    const float4 v = *reinterpret_cast<const float4*>(cb + (size_t)k * NC + l * 4);
    double s = (double)v.x + (double)v.y + (double)v.z + (double)v.w;
    #pragma unroll
    for (int off = 32; off > 0; off >>= 1) s += __shfl_xor(s, off);
    if (l == 0) ws[k] = s;
    if (blockIdx.x == 0 && threadIdx.x == 0) ws[NK] = 0.0;   // kld accumulator
}

// gs_main: r16 structure (512 thr, 8 waves x 8 tokens; measured best) + own-slab
// mat zero-fill folded into the token loop (8 NT dword stores/thread/iter, hidden
// under Phase B latency; barriers order zero -> scatter).
__global__ void __launch_bounds__(512, 4)
gs_main(const float* __restrict__ feats, const float* __restrict__ gumbel,
        const float* __restrict__ cb, double* __restrict__ ws,
        float* __restrict__ out) {
    __shared__ double part[8][64];
    __shared__ float  sw_f[NK];
    __shared__ double sf_d[64];
    __shared__ float  sf_f[64];
    __shared__ int    kcnt[64];
    __shared__ int    klist[64][25];
    __shared__ float  wlist[64][25];
    __shared__ double kldp[8];

    const int tid = threadIdx.x;
    const int l   = tid & 63;          // lane
    const int w   = tid >> 6;          // wave 0..7
    const int b   = blockIdx.x >> 6;   // 64 blocks per batch
    const int n0  = (blockIdx.x & 63) * 64;

    // ---- Phase A: sf[tok] = sum_c feats[b,c,n0+tok] (f64); sw -> LDS f32 ----
    {
        const float* fp = feats + ((size_t)b * NC + w * 32) * NHW + n0 + l;
        double s = 0.0;
        #pragma unroll
        for (int i = 0; i < 32; ++i) s += (double)fp[(size_t)i * NHW];
        part[w][l] = s;
        sw_f[tid] = (float)ws[tid];
        __syncthreads();
        if (tid < 64) {
            double a = 0.0;
            #pragma unroll
            for (int i = 0; i < 8; ++i) a += part[i][tid];
            sf_d[tid] = a; sf_f[tid] = (float)a;
            kcnt[tid] = 0;
        }
        __syncthreads();
    }

    // hoist this lane's 8 sw values (same for all its tokens)
    float swreg[8];
    #pragma unroll
    for (int jj = 0; jj < 8; ++jj) swreg[jj] = sw_f[l + 64 * jj];

    // own mat slab base: rows k=0..511, cols n0+l (this thread zeroes col l)
    float* zbase = out + OFF_MAT + (size_t)b * NK * NHW + n0 + l;

    // ---- Phase B: 8 tokens per wave; k = l + 64*jj (256B coalesced g loads) ----
    double kld_wave = 0.0;
    float gc[8], gn[8];
    {
        const float* gp = gumbel + ((size_t)(b * NHW) + n0 + w * 8) * NK;
        #pragma unroll
        for (int jj = 0; jj < 8; ++jj) gc[jj] = gp[l + 64 * jj];
    }
    #pragma unroll
    for (int i = 0; i < 8; ++i) {
        const int tt = w * 8 + i;
        const int n  = n0 + tt;
        if (i < 7) {                        // prefetch next token's row
            const float* gpn = gumbel + ((size_t)(b * NHW) + n + 1) * NK;
            #pragma unroll
            for (int jj = 0; jj < 8; ++jj) gn[jj] = gpn[l + 64 * jj];
        }
        // zero 64 rows of own mat slab this iteration (hidden under compute;
        // wave-coalesced 256B rows; barriers below order these before the scatter)
        #pragma unroll
        for (int j = 0; j < 8; ++j)
            __builtin_nontemporal_store(0.f, zbase + (size_t)(i * 64 + j * 8 + w) * NHW);
        const float sft = sf_f[tt];
        float y[8];
        float M = -1.0e30f, YS = -1.0e30f; int KB = 0;
        float E = 0.f, T = 0.f;
        #pragma unroll
        for (int jj = 0; jj < 8; ++jj) {    // hot loop: pure VALU, k ascending
            const int k = l + 64 * jj;
            const float d = sft - swreg[jj];
            const float logit = __expf(-d * d);
            const float yy = logit + gc[jj];
            y[jj] = yy;
            // e^logit - 1 = logit*h (5th order): E rel err ~4e-6
            const float h = fmaf(logit, fmaf(logit, fmaf(logit, fmaf(logit,
                              1.f/120.f, 1.f/24.f), 1.f/6.f), 0.5f), 1.f);
            const float xh = logit * h;
            E += xh;
            T = fmaf(logit, 1.f + xh, T);
            if (yy > M) { YS = M; M = yy; KB = k; }      // strict >: lowest k on ties
            else YS = fmaxf(YS, yy);
        }
        // merged 64-lane reduce: 4 DPP + 1 swizzle + 1 shfl (argmax/2nd/E/T)
        #define BSTEP(GF, GI) { \
            const float oM = GF(M); const int oK = GI(KB); \
            const float oY = GF(YS); const float oE = GF(E); const float oT = GF(T); \
            const float nys = fmaxf(fmaxf(YS, oY), fminf(M, oM)); \
            if (oM > M || (oM == M && oK < KB)) { M = oM; KB = oK; } \
            YS = nys; E += oE; T += oT; }
        BSTEP(fdpp<0xB1>,  idpp<0xB1>)     // xor 1
        BSTEP(fdpp<0x4E>,  idpp<0x4E>)     // xor 2
        BSTEP(fdpp<0x141>, idpp<0x141>)    // xor 7 (row half mirror)
        BSTEP(fdpp<0x140>, idpp<0x140>)    // xor 15 (row mirror)
        BSTEP(fswz16,      iswz16)         // xor 16 (DS)
        #define SH32F(x) __shfl_xor(x, 32)
        #define SH32I(x) __shfl_xor(x, 32)
        BSTEP(SH32F, SH32I)                // xor 32 (DS, cross-half)
        #undef SH32F
        #undef SH32I
        #undef BSTEP
        E += 512.f;

        // rare exact f64 argmax (wave-uniform); f32 y err ~1e-5 << 5e-3 gap
        if (M - YS < 5e-3f) {
            const double sfd = sf_d[tt];
            double ym64 = -1.0e300; int kb64 = 0;
            #pragma unroll
            for (int jj = 0; jj < 8; ++jj) {
                const int k = l + 64 * jj;
                const double dd = sfd - ws[k];
                const double aff = dd * dd;
                const double lg = (aff < 45.0) ? exp(-aff) : 0.0;   // <3e-20 invisible
                const double yy = lg + (double)gc[jj];
                if (yy > ym64) { ym64 = yy; kb64 = k; }
            }
            #pragma unroll
            for (int off = 1; off < 64; off <<= 1) {
                const double oy = __shfl_xor(ym64, off);
                const int    ok = __shfl_xor(kb64, off);
                if (oy > ym64 || (oy == ym64 && ok < kb64)) { ym64 = oy; kb64 = ok; }
            }
            KB = kb64;
        }
        if (l == 0) {
            out[OFF_CW + (size_t)b * NHW + n] = (float)KB;
            // kld_tok = T/E + ln512 - lnE (eps=1e-10 negligible)
            kld_wave += (double)(T / E + 6.2383246250395075f - logf(E));
        }

        // candidates: y > M-0.17 (<=> p > 4e-8, ~1.3/token): exp only when needed
        const float thrM = M - 0.17f;
        #pragma unroll
        for (int jj = 0; jj < 8; ++jj) {
            if (y[jj] > thrM) {
                const float p = __expf((y[jj] - M) * 100.0f);
                const int idx = atomicAdd(&kcnt[tt], 1);
                if (idx < 24) { klist[tt][idx] = l + 64 * jj; wlist[tt][idx] = p; }
            }
        }
        #pragma unroll
        for (int jj = 0; jj < 8; ++jj) gc[jj] = gn[jj];
    }
    if (l == 0) kldp[w] = kld_wave;
    __syncthreads();
    if (tid == 0) {
        double acc = 0.0;
        #pragma unroll
        for (int i = 0; i < 8; ++i) acc += kldp[i];
        atomicAdd(&ws[NK], acc);            // one global atomic per block (no fence)
    }

    // ---- Finalize: per-token S from list, normalize in LDS, sparse mat scatter ----
    // (__syncthreads above drained the zero-stores: scatter safely overwrites)
    if (tid < 64) {
        const int cnt = min(kcnt[tid], 24);
        float S = 0.f;
        for (int e = 0; e < cnt; ++e) S += wlist[tid][e];
        const float inv = 1.f / S;          // excluded mass < 512*4e-8 = 2e-5 rel
        float* orow = out + OFF_MAT + ((size_t)b * NK) * NHW + n0 + tid;
        for (int e = 0; e < cnt; ++e) {
            const float wgt = wlist[tid][e] * inv;
            wlist[tid][e] = wgt;
            orow[(size_t)klist[tid][e] * NHW] = wgt;   // sparse scatter on zeroed slab
        }
        kcnt[tid] = cnt;
    }
    __syncthreads();

    // ---- Phase D: sel_codewords (B,C,N) from sparse list (NT stores, 256B runs) ----
    {
        const int cnt = kcnt[l];            // lane l = token l
        #pragma unroll
        for (int half = 0; half < 2; ++half) {
            float acc[16];
            #pragma unroll
            for (int i2 = 0; i2 < 16; ++i2) acc[i2] = 0.f;
            for (int e = 0; e < cnt; ++e) {
                const int k = klist[l][e];
                const float wgt = wlist[l][e];
                const float4* cr = reinterpret_cast<const float4*>(
                    cb + (size_t)k * NC + w * 32 + half * 16);
                #pragma unroll
                for (int q = 0; q < 4; ++q) {
                    const float4 v = cr[q];
                    acc[q * 4 + 0] += wgt * v.x; acc[q * 4 + 1] += wgt * v.y;
                    acc[q * 4 + 2] += wgt * v.z; acc[q * 4 + 3] += wgt * v.w;
                }
            }
            float* basep = out + OFF_SEL + ((size_t)b * NC + w * 32 + half * 16) * NHW + n0 + l;
            #pragma unroll
            for (int i2 = 0; i2 < 16; ++i2)
                __builtin_nontemporal_store(acc[i2], basep + (size_t)i2 * NHW);
        }
    }
}

__global__ void gumbel_fin(const double* __restrict__ ws, float* __restrict__ out) {
    out[OFF_KLD] = (float)(ws[NK] * (1.0 / 32768.0));
}

extern "C" void kernel_launch(void* const* d_in, const int* in_sizes, int n_in,
                              void* d_out, int out_size, void* d_ws, size_t ws_size,
                              hipStream_t stream) {
    const float* feats = (const float*)d_in[0];
    const float* cb    = (const float*)d_in[1];
    const float* gum   = (const float*)d_in[2];
    double* ws = (double*)d_ws;
    float* out = (float*)d_out;
    prep<<<128, 256, 0, stream>>>(cb, ws);
    gs_main<<<512, 512, 0, stream>>>(feats, gum, cb, ws, out);
    gumbel_fin<<<1, 1, 0, stream>>>(ws, out);
}

// Round 20
// 58.118 us; speedup vs baseline: 1.1151x; 1.1151x over previous
//
#include <hip/hip_runtime.h>
#include <math.h>
#include <stdint.h>

// Problem dims
#define NB  8
#define NC  256
#define NHW 4096   // H*W
#define NK  512

// d_out float offsets (outputs concatenated in return order)
#define OFF_SEL 0ULL
#define OFF_CW  8388608ULL              // NB*NC*NHW
#define OFF_KLD 8421376ULL              // + NB*NHW
#define OFF_MAT 8421377ULL              // + 1
#define MAT_COUNT 16777216ULL           // NB*NK*NHW
#define OUT_TOTAL (OFF_MAT + MAT_COUNT) // 25198593

typedef float f4v __attribute__((ext_vector_type(4)));

// ws layout: double sw[512]; double kld_accum;  (4104 bytes)

// DPP helpers: xor1=0xB1, xor2=0x4E, xor7(row_half_mirror)=0x141, xor15(row_mirror)=0x140
template <int C>
__device__ __forceinline__ float fdpp(float x) {
    return __int_as_float(__builtin_amdgcn_update_dpp(0, __float_as_int(x), C, 0xF, 0xF, true));
}
template <int C>
__device__ __forceinline__ int idpp(int x) {
    return __builtin_amdgcn_update_dpp(0, x, C, 0xF, 0xF, true);
}
__device__ __forceinline__ float fswz16(float x) {   // lane ^ 16
    return __int_as_float(__builtin_amdgcn_ds_swizzle(__float_as_int(x), 0x401F));
}
__device__ __forceinline__ int iswz16(int x) {
    return __builtin_amdgcn_ds_swizzle(x, 0x401F);
}

// Fused: zero-fill mat region (NT float4 stream) + codebook channel-sum prep
// (blocks 0..127) + ws kld zeroing (block 0).  [measured best, r16]
__global__ void zprep(const float* __restrict__ cb, double* __restrict__ ws,
                      float* __restrict__ out) {
    const size_t base4 = 2105345ULL;            // 8421380/4 : first 16B-aligned float4
    const size_t n4    = 4194303ULL;
    size_t i = (size_t)blockIdx.x * blockDim.x + threadIdx.x;
    const size_t stride = (size_t)gridDim.x * blockDim.x;
    f4v* o4 = reinterpret_cast<f4v*>(out) + base4;
    const f4v z = {0.f, 0.f, 0.f, 0.f};
    for (; i < n4; i += stride) __builtin_nontemporal_store(z, o4 + i);
    if (blockIdx.x == 0 && threadIdx.x < 4) {
        out[OFF_MAT + threadIdx.x] = 0.f;       // head floats
        if (threadIdx.x == 0) {
            out[OUT_TOTAL - 1] = 0.f;           // tail float
            ws[NK] = 0.0;                       // kld accumulator
        }
    }
    if (blockIdx.x < 128) {                     // codebook prep
        const int l = threadIdx.x & 63;
        const int w = threadIdx.x >> 6;
        const int k = blockIdx.x * 4 + w;
        const float4 v = *reinterpret_cast<const float4*>(cb + (size_t)k * NC + l * 4);
        double s = (double)v.x + (double)v.y + (double)v.z + (double)v.w;
        #pragma unroll
        for (int off = 32; off > 0; off >>= 1) s += __shfl_xor(s, off);
        if (l == 0) ws[k] = s;
    }
}

// gs_main: r12/r16 structure (measured best: 48 VGPR, no spills, 34 MB write,
// profiled ~59 us). No device fences; kld via one atomicAdd per block.
__global__ void __launch_bounds__(512, 4)
gs_main(const float* __restrict__ feats, const float* __restrict__ gumbel,
        const float* __restrict__ cb, double* __restrict__ ws,
        float* __restrict__ out) {
    __shared__ double part[8][64];
    __shared__ float  sw_f[NK];
    __shared__ double sf_d[64];
    __shared__ float  sf_f[64];
    __shared__ int    kcnt[64];
    __shared__ int    klist[64][25];
    __shared__ float  wlist[64][25];
    __shared__ double kldp[8];

    const int tid = threadIdx.x;
    const int l   = tid & 63;          // lane
    const int w   = tid >> 6;          // wave 0..7
    const int b   = blockIdx.x >> 6;   // 64 blocks per batch
    const int n0  = (blockIdx.x & 63) * 64;

    // ---- Phase A: sf[tok] = sum_c feats[b,c,n0+tok] (f64); sw -> LDS f32 ----
    {
        const float* fp = feats + ((size_t)b * NC + w * 32) * NHW + n0 + l;
        double s = 0.0;
        #pragma unroll
        for (int i = 0; i < 32; ++i) s += (double)fp[(size_t)i * NHW];
        part[w][l] = s;
        sw_f[tid] = (float)ws[tid];
        __syncthreads();
        if (tid < 64) {
            double a = 0.0;
            #pragma unroll
            for (int i = 0; i < 8; ++i) a += part[i][tid];
            sf_d[tid] = a; sf_f[tid] = (float)a;
            kcnt[tid] = 0;
        }
        __syncthreads();
    }

    // hoist this lane's 8 sw values (same for all its tokens)
    float swreg[8];
    #pragma unroll
    for (int jj = 0; jj < 8; ++jj) swreg[jj] = sw_f[l + 64 * jj];

    // ---- Phase B: 8 tokens per wave; k = l + 64*jj (256B coalesced g loads) ----
    double kld_wave = 0.0;
    float gc[8], gn[8];
    {
        const float* gp = gumbel + ((size_t)(b * NHW) + n0 + w * 8) * NK;
        #pragma unroll
        for (int jj = 0; jj < 8; ++jj) gc[jj] = gp[l + 64 * jj];
    }
    #pragma unroll
    for (int i = 0; i < 8; ++i) {
        const int tt = w * 8 + i;
        const int n  = n0 + tt;
        if (i < 7) {                        // prefetch next token's row
            const float* gpn = gumbel + ((size_t)(b * NHW) + n + 1) * NK;
            #pragma unroll
            for (int jj = 0; jj < 8; ++jj) gn[jj] = gpn[l + 64 * jj];
        }
        const float sft = sf_f[tt];
        float y[8];
        float M = -1.0e30f, YS = -1.0e30f; int KB = 0;
        float E = 0.f, T = 0.f;
        #pragma unroll
        for (int jj = 0; jj < 8; ++jj) {    // hot loop: pure VALU, k ascending
            const int k = l + 64 * jj;
            const float d = sft - swreg[jj];
            const float logit = __expf(-d * d);
            const float yy = logit + gc[jj];
            y[jj] = yy;
            // e^logit - 1 = logit*h (5th order): E rel err ~4e-6
            const float h = fmaf(logit, fmaf(logit, fmaf(logit, fmaf(logit,
                              1.f/120.f, 1.f/24.f), 1.f/6.f), 0.5f), 1.f);
            const float xh = logit * h;
            E += xh;
            T = fmaf(logit, 1.f + xh, T);
            if (yy > M) { YS = M; M = yy; KB = k; }      // strict >: lowest k on ties
            else YS = fmaxf(YS, yy);
        }
        // merged 64-lane reduce: 4 DPP + 1 swizzle + 1 shfl (argmax/2nd/E/T)
        #define BSTEP(GF, GI) { \
            const float oM = GF(M); const int oK = GI(KB); \
            const float oY = GF(YS); const float oE = GF(E); const float oT = GF(T); \
            const float nys = fmaxf(fmaxf(YS, oY), fminf(M, oM)); \
            if (oM > M || (oM == M && oK < KB)) { M = oM; KB = oK; } \
            YS = nys; E += oE; T += oT; }
        BSTEP(fdpp<0xB1>,  idpp<0xB1>)     // xor 1
        BSTEP(fdpp<0x4E>,  idpp<0x4E>)     // xor 2
        BSTEP(fdpp<0x141>, idpp<0x141>)    // xor 7 (row half mirror)
        BSTEP(fdpp<0x140>, idpp<0x140>)    // xor 15 (row mirror)
        BSTEP(fswz16,      iswz16)         // xor 16 (DS)
        #define SH32F(x) __shfl_xor(x, 32)
        #define SH32I(x) __shfl_xor(x, 32)
        BSTEP(SH32F, SH32I)                // xor 32 (DS, cross-half)
        #undef SH32F
        #undef SH32I
        #undef BSTEP
        E += 512.f;

        // rare exact f64 argmax (wave-uniform); f32 y err ~1e-5 << 5e-3 gap
        if (M - YS < 5e-3f) {
            const double sfd = sf_d[tt];
            double ym64 = -1.0e300; int kb64 = 0;
            #pragma unroll
            for (int jj = 0; jj < 8; ++jj) {
                const int k = l + 64 * jj;
                const double dd = sfd - ws[k];
                const double aff = dd * dd;
                const double lg = (aff < 45.0) ? exp(-aff) : 0.0;   // <3e-20 invisible
                const double yy = lg + (double)gc[jj];
                if (yy > ym64) { ym64 = yy; kb64 = k; }
            }
            #pragma unroll
            for (int off = 1; off < 64; off <<= 1) {
                const double oy = __shfl_xor(ym64, off);
                const int    ok = __shfl_xor(kb64, off);
                if (oy > ym64 || (oy == ym64 && ok < kb64)) { ym64 = oy; kb64 = ok; }
            }
            KB = kb64;
        }
        if (l == 0) {
            out[OFF_CW + (size_t)b * NHW + n] = (float)KB;
            // kld_tok = T/E + ln512 - lnE (eps=1e-10 negligible)
            kld_wave += (double)(T / E + 6.2383246250395075f - logf(E));
        }

        // candidates: y > M-0.17 (<=> p > 4e-8, ~1.3/token): exp only when needed
        const float thrM = M - 0.17f;
        #pragma unroll
        for (int jj = 0; jj < 8; ++jj) {
            if (y[jj] > thrM) {
                const float p = __expf((y[jj] - M) * 100.0f);
                const int idx = atomicAdd(&kcnt[tt], 1);
                if (idx < 24) { klist[tt][idx] = l + 64 * jj; wlist[tt][idx] = p; }
            }
        }
        #pragma unroll
        for (int jj = 0; jj < 8; ++jj) gc[jj] = gn[jj];
    }
    if (l == 0) kldp[w] = kld_wave;
    __syncthreads();
    if (tid == 0) {
        double acc = 0.0;
        #pragma unroll
        for (int i = 0; i < 8; ++i) acc += kldp[i];
        atomicAdd(&ws[NK], acc);            // one global atomic per block (no fence)
    }

    // ---- Finalize: per-token S from list, normalize in LDS, sparse mat scatter ----
    if (tid < 64) {
        const int cnt = min(kcnt[tid], 24);
        float S = 0.f;
        for (int e = 0; e < cnt; ++e) S += wlist[tid][e];
        const float inv = 1.f / S;          // excluded mass < 512*4e-8 = 2e-5 rel
        float* orow = out + OFF_MAT + ((size_t)b * NK) * NHW + n0 + tid;
        for (int e = 0; e < cnt; ++e) {
            const float wgt = wlist[tid][e] * inv;
            wlist[tid][e] = wgt;
            orow[(size_t)klist[tid][e] * NHW] = wgt;   // sparse scatter on zprep bg
        }
        kcnt[tid] = cnt;
    }
    __syncthreads();

    // ---- Phase D: sel_codewords (B,C,N) from sparse list (NT stores, 256B runs) ----
    {
        const int cnt = kcnt[l];            // lane l = token l
        #pragma unroll
        for (int half = 0; half < 2; ++half) {
            float acc[16];
            #pragma unroll
            for (int i2 = 0; i2 < 16; ++i2) acc[i2] = 0.f;
            for (int e = 0; e < cnt; ++e) {
                const int k = klist[l][e];
                const float wgt = wlist[l][e];
                const float4* cr = reinterpret_cast<const float4*>(
                    cb + (size_t)k * NC + w * 32 + half * 16);
                #pragma unroll
                for (int q = 0; q < 4; ++q) {
                    const float4 v = cr[q];
                    acc[q * 4 + 0] += wgt * v.x; acc[q * 4 + 1] += wgt * v.y;
                    acc[q * 4 + 2] += wgt * v.z; acc[q * 4 + 3] += wgt * v.w;
                }
            }
            float* basep = out + OFF_SEL + ((size_t)b * NC + w * 32 + half * 16) * NHW + n0 + l;
            #pragma unroll
            for (int i2 = 0; i2 < 16; ++i2)
                __builtin_nontemporal_store(acc[i2], basep + (size_t)i2 * NHW);
        }
    }
}

__global__ void gumbel_fin(const double* __restrict__ ws, float* __restrict__ out) {
    out[OFF_KLD] = (float)(ws[NK] * (1.0 / 32768.0));
}

extern "C" void kernel_launch(void* const* d_in, const int* in_sizes, int n_in,
                              void* d_out, int out_size, void* d_ws, size_t ws_size,
                              hipStream_t stream) {
    const float* feats = (const float*)d_in[0];
    const float* cb    = (const float*)d_in[1];
    const float* gum   = (const float*)d_in[2];
    double* ws = (double*)d_ws;
    float* out = (float*)d_out;
    zprep<<<2048, 256, 0, stream>>>(cb, ws, out);
    gs_main<<<512, 512, 0, stream>>>(feats, gum, cb, ws, out);
    gumbel_fin<<<1, 1, 0, stream>>>(ws, out);
}